// Round 1
// baseline (71.736 us; speedup 1.0000x reference)
//
#include <hip/hip_runtime.h>

#define K_OBJ 64
#define NCOLR 10
#define HID 128
#define GH 2048
#define GWID 2048
#define NPIX (GH * GWID)
#define LN_EPS 1e-5f

// ws layout (ints): [0,640) hist[64][10], [640,704) ymin, [704,768) ymax,
//                   [768,832) xmin, [832,896) xmax
// floats: feats[64][128] at byte offset 4096

__global__ void init_kernel(int* __restrict__ acc) {
    int t = threadIdx.x;
    if (t < 640) acc[t] = 0;
    else if (t < 704) acc[t] = 0x7fffffff;      // ymin
    else if (t < 768) acc[t] = (int)0x80000000; // ymax
    else if (t < 832) acc[t] = 0x7fffffff;      // xmin
    else if (t < 896) acc[t] = (int)0x80000000; // xmax
}

#define RB_BLOCKS 1024
#define RB_TPB 256

__global__ __launch_bounds__(RB_TPB) void reduce_kernel(
        const int4* __restrict__ grid4, const int4* __restrict__ lab4,
        int* __restrict__ acc) {
    __shared__ int s_hist[K_OBJ * NCOLR];
    __shared__ int s_ymin[K_OBJ], s_ymax[K_OBJ], s_xmin[K_OBJ], s_xmax[K_OBJ];
    const int tid = threadIdx.x;
    for (int i = tid; i < K_OBJ * NCOLR; i += RB_TPB) s_hist[i] = 0;
    if (tid < K_OBJ) {
        s_ymin[tid] = 0x7fffffff; s_ymax[tid] = (int)0x80000000;
        s_xmin[tid] = 0x7fffffff; s_xmax[tid] = (int)0x80000000;
    }
    __syncthreads();

    const int lane = tid & 63;
    const int gw = blockIdx.x * (RB_TPB / 64) + (tid >> 6);
    const int ITER = NPIX / (RB_BLOCKS * RB_TPB * 4);  // = 4
    for (int it = 0; it < ITER; ++it) {
        const int ci = gw * ITER + it;
        const int base = ci * 256;              // chunk of 256 contiguous pixels
        const int4 g  = grid4[(base >> 2) + lane];
        const int4 lb = lab4[(base >> 2) + lane];
        const int row = base >> 11;             // GWID = 2048
        const int colbase = base & (GWID - 1);
        #pragma unroll
        for (int j = 0; j < 4; ++j) {
            const int lj = (j == 0) ? lb.x : (j == 1) ? lb.y : (j == 2) ? lb.z : lb.w;
            const int cj = (j == 0) ? g.x  : (j == 1) ? g.y  : (j == 2) ? g.z  : g.w;
            const bool pred = ((unsigned)lj < (unsigned)K_OBJ);
            const unsigned long long act = __ballot(pred);
            if (act == 0ull) continue;
            const int first = __builtin_ctzll(act);
            const int lab0 = __shfl(lj, first);
            const bool uni = __all((!pred) || (lj == lab0));
            if (uni) {
                if (lane == first) {
                    const int last = 63 - __builtin_clzll(act);
                    atomicMin(&s_xmin[lab0], colbase + first * 4 + j);
                    atomicMax(&s_xmax[lab0], colbase + last * 4 + j);
                    atomicMin(&s_ymin[lab0], row);
                    atomicMax(&s_ymax[lab0], row);
                }
                const int key = pred ? cj : -1;
                #pragma unroll
                for (int c = 0; c < NCOLR; ++c) {
                    const unsigned long long m = __ballot(key == c);
                    if (m && lane == first)
                        atomicAdd(&s_hist[lab0 * NCOLR + c], __popcll(m));
                }
            } else {
                // generic slow path (mixed labels in wave)
                if (pred) {
                    atomicAdd(&s_hist[lj * NCOLR + cj], 1);
                    const int xj = colbase + lane * 4 + j;
                    atomicMin(&s_xmin[lj], xj);
                    atomicMax(&s_xmax[lj], xj);
                    atomicMin(&s_ymin[lj], row);
                    atomicMax(&s_ymax[lj], row);
                }
            }
        }
    }
    __syncthreads();
    for (int i = tid; i < K_OBJ * NCOLR; i += RB_TPB) {
        const int v = s_hist[i];
        if (v) atomicAdd(&acc[i], v);
    }
    if (tid < K_OBJ) {
        if (s_ymin[tid] != 0x7fffffff)      atomicMin(&acc[640 + tid], s_ymin[tid]);
        if (s_ymax[tid] != (int)0x80000000) atomicMax(&acc[704 + tid], s_ymax[tid]);
        if (s_xmin[tid] != 0x7fffffff)      atomicMin(&acc[768 + tid], s_xmin[tid]);
        if (s_xmax[tid] != (int)0x80000000) atomicMax(&acc[832 + tid], s_xmax[tid]);
    }
}

__global__ __launch_bounds__(HID) void feats_kernel(
        const int* __restrict__ acc, const float* __restrict__ emb,
        const float* __restrict__ w1, const float* __restrict__ b1,
        const float* __restrict__ w2, const float* __restrict__ b2,
        float* __restrict__ feats) {
    const int k = blockIdx.x;   // object 0..63
    const int d = threadIdx.x;  // dim 0..127
    __shared__ float s_hid[HID];
    __shared__ float s_hist[NCOLR];
    __shared__ float s_geo[4];  // h, w, area_frac, count
    if (d < NCOLR) s_hist[d] = (float)acc[k * NCOLR + d];
    if (d == 0) {
        int cnt = 0;
        for (int c = 0; c < NCOLR; ++c) cnt += acc[k * NCOLR + c];
        s_geo[0] = (float)(acc[704 + k] - acc[640 + k] + 1);
        s_geo[1] = (float)(acc[832 + k] - acc[768 + k] + 1);
        s_geo[2] = (float)cnt / (float)NPIX;
        s_geo[3] = (float)cnt;
    }
    __syncthreads();
    float hv = b1[d] + s_geo[0] * w1[d * 3 + 0] + s_geo[1] * w1[d * 3 + 1]
             + s_geo[2] * w1[d * 3 + 2];
    s_hid[d] = fmaxf(hv, 0.0f);
    __syncthreads();
    float geo = b2[d];
    #pragma unroll 8
    for (int j = 0; j < HID; ++j) geo += s_hid[j] * w2[d * HID + j];
    float ce = 0.0f;
    #pragma unroll
    for (int c = 0; c < NCOLR; ++c) ce += s_hist[c] * emb[c * HID + d];
    const float cnt = s_geo[3];
    ce = (cnt > 0.0f) ? (ce / cnt) : 0.0f;
    feats[k * HID + d] = 0.5f * (ce + geo);
}

__global__ __launch_bounds__(HID) void attn_kernel(
        const float* __restrict__ feats, const float* __restrict__ query,
        const float* __restrict__ wqkv, const float* __restrict__ bqkv,
        const float* __restrict__ wo, const float* __restrict__ bo,
        const float* __restrict__ lnw, const float* __restrict__ lnb,
        float* __restrict__ out) {
    __shared__ float s_feats[K_OBJ][HID];
    __shared__ float s_q[HID], s_qp[HID], s_u[4][HID], s_cb[4];
    __shared__ float s_attn[4][K_OBJ], s_pool[4][HID], s_oh[HID];
    __shared__ float s_red[2];
    const int tid = threadIdx.x;
    for (int i = tid; i < K_OBJ * HID; i += HID) ((float*)s_feats)[i] = feats[i];
    s_q[tid] = query[tid];
    __syncthreads();
    const float scale = 0.17677669529663687f;  // 1/sqrt(32)
    for (int l = 0; l < 2; ++l) {
        const float* W  = wqkv + l * 384 * HID;
        const float* bq = bqkv + l * 384;
        // q projection: thread tid computes qp[tid]
        float a = bq[tid];
        for (int j = 0; j < HID; ++j) a += s_q[j] * W[tid * HID + j];
        s_qp[tid] = a;
        __syncthreads();
        // u[h][j] = sum_{d in head h} qp[d] * Wk[d][j]   (thread = j)
        #pragma unroll
        for (int h = 0; h < 4; ++h) {
            float u = 0.0f;
            for (int dd = 0; dd < 32; ++dd)
                u += s_qp[h * 32 + dd] * W[(HID + h * 32 + dd) * HID + tid];
            s_u[h][tid] = u;
        }
        if (tid < 4) {
            float cb = 0.0f;
            for (int dd = 0; dd < 32; ++dd)
                cb += s_qp[tid * 32 + dd] * bq[HID + tid * 32 + dd];
            s_cb[tid] = cb;
        }
        __syncthreads();
        // scores[h][k] = scale * (feats[k] . u[h] + cb[h])
        for (int idx = tid; idx < 256; idx += HID) {
            const int h = idx >> 6, k = idx & 63;
            float sc = s_cb[h];
            for (int j = 0; j < HID; ++j) sc += s_feats[k][j] * s_u[h][j];
            s_attn[h][k] = sc * scale;
        }
        __syncthreads();
        // softmax per head: 32-lane group per head, each lane owns k=g, g+32
        {
            const int h = tid >> 5, g = tid & 31;
            const float v0 = s_attn[h][g], v1 = s_attn[h][g + 32];
            float m = fmaxf(v0, v1);
            for (int off = 16; off >= 1; off >>= 1)
                m = fmaxf(m, __shfl_xor(m, off, 32));
            const float e0 = expf(v0 - m), e1 = expf(v1 - m);
            float s = e0 + e1;
            for (int off = 16; off >= 1; off >>= 1) s += __shfl_xor(s, off, 32);
            s_attn[h][g] = e0 / s;
            s_attn[h][g + 32] = e1 / s;
        }
        __syncthreads();
        // pooled[h][j] = sum_k attn[h][k] * feats[k][j]   (thread = j)
        #pragma unroll
        for (int h = 0; h < 4; ++h) {
            float p = 0.0f;
            for (int k = 0; k < K_OBJ; ++k) p += s_attn[h][k] * s_feats[k][tid];
            s_pool[h][tid] = p;
        }
        __syncthreads();
        // oh[d] = Wv[d] . pooled[head(d)] + bv[d]   (thread = d)
        {
            const int h = tid >> 5;
            float o = bq[256 + tid];
            for (int j = 0; j < HID; ++j)
                o += W[(256 + tid) * HID + j] * s_pool[h][j];
            s_oh[tid] = o;
        }
        __syncthreads();
        // output proj + residual + layernorm
        float o = bo[l * HID + tid];
        for (int j = 0; j < HID; ++j) o += s_oh[j] * wo[l * HID * HID + tid * HID + j];
        const float r = s_q[tid] + o;
        float v = r;
        for (int off = 32; off >= 1; off >>= 1) v += __shfl_xor(v, off, 64);
        if ((tid & 63) == 0) s_red[tid >> 6] = v;
        __syncthreads();
        const float mu = (s_red[0] + s_red[1]) * (1.0f / HID);
        const float dv = r - mu;
        float v2 = dv * dv;
        __syncthreads();
        for (int off = 32; off >= 1; off >>= 1) v2 += __shfl_xor(v2, off, 64);
        if ((tid & 63) == 0) s_red[tid >> 6] = v2;
        __syncthreads();
        const float var = (s_red[0] + s_red[1]) * (1.0f / HID);
        const float qn = dv * rsqrtf(var + LN_EPS) * lnw[l * HID + tid]
                       + lnb[l * HID + tid];
        __syncthreads();
        s_q[tid] = qn;
        __syncthreads();
    }
    out[tid] = s_q[tid];
}

extern "C" void kernel_launch(void* const* d_in, const int* in_sizes, int n_in,
                              void* d_out, int out_size, void* d_ws, size_t ws_size,
                              hipStream_t stream) {
    const int4* grid4 = (const int4*)d_in[0];
    const int4* lab4  = (const int4*)d_in[1];
    const float* emb  = (const float*)d_in[2];
    const float* gw1  = (const float*)d_in[3];
    const float* gb1  = (const float*)d_in[4];
    const float* gw2  = (const float*)d_in[5];
    const float* gb2  = (const float*)d_in[6];
    const float* query = (const float*)d_in[7];
    const float* wqkv = (const float*)d_in[8];
    const float* bqkv = (const float*)d_in[9];
    const float* wo   = (const float*)d_in[10];
    const float* bo   = (const float*)d_in[11];
    const float* lnw  = (const float*)d_in[12];
    const float* lnb  = (const float*)d_in[13];

    int* acc = (int*)d_ws;
    float* feats = (float*)((char*)d_ws + 4096);

    hipLaunchKernelGGL(init_kernel, dim3(1), dim3(1024), 0, stream, acc);
    hipLaunchKernelGGL(reduce_kernel, dim3(RB_BLOCKS), dim3(RB_TPB), 0, stream,
                       grid4, lab4, acc);
    hipLaunchKernelGGL(feats_kernel, dim3(K_OBJ), dim3(HID), 0, stream,
                       acc, emb, gw1, gb1, gw2, gb2, feats);
    hipLaunchKernelGGL(attn_kernel, dim3(1), dim3(HID), 0, stream,
                       feats, query, wqkv, bqkv, wo, bo, lnw, lnb, (float*)d_out);
}

// Round 2
// 56.793 us; speedup vs baseline: 1.2631x; 1.2631x over previous
//
#include <hip/hip_runtime.h>

#define K_OBJ 64
#define NCOLR 10
#define HID 128
#define GH 2048
#define GWID 2048
#define NPIX (GH * GWID)
#define LN_EPS 1e-5f

// ws layout (ints): [0,640) hist[64][10], [640,704) ymin, [704,768) ymax,
//                   [768,832) xmin, [832,896) xmax
// floats: feats[64][128] at byte offset 4096

__global__ void init_kernel(int* __restrict__ acc) {
    int t = threadIdx.x;
    if (t < 640) acc[t] = 0;
    else if (t < 704) acc[t] = 0x7fffffff;      // ymin
    else if (t < 768) acc[t] = (int)0x80000000; // ymax
    else if (t < 832) acc[t] = 0x7fffffff;      // xmin
    else if (t < 896) acc[t] = (int)0x80000000; // xmax
}

#define RB_BLOCKS 1024
#define RB_TPB 256

__global__ __launch_bounds__(RB_TPB) void reduce_kernel(
        const int4* __restrict__ grid4, const int4* __restrict__ lab4,
        int* __restrict__ acc) {
    __shared__ int s_hist[K_OBJ * NCOLR];
    __shared__ int s_ymin[K_OBJ], s_ymax[K_OBJ], s_xmin[K_OBJ], s_xmax[K_OBJ];
    const int tid = threadIdx.x;
    for (int i = tid; i < K_OBJ * NCOLR; i += RB_TPB) s_hist[i] = 0;
    if (tid < K_OBJ) {
        s_ymin[tid] = 0x7fffffff; s_ymax[tid] = (int)0x80000000;
        s_xmin[tid] = 0x7fffffff; s_xmax[tid] = (int)0x80000000;
    }
    __syncthreads();

    const int lane = tid & 63;
    const int gw = blockIdx.x * (RB_TPB / 64) + (tid >> 6);
    const int ITER = NPIX / (RB_BLOCKS * RB_TPB * 4);  // = 4
    for (int it = 0; it < ITER; ++it) {
        const int ci = gw * ITER + it;
        const int base = ci * 256;              // chunk of 256 contiguous pixels
        const int4 g  = grid4[(base >> 2) + lane];
        const int4 lb = lab4[(base >> 2) + lane];
        const int row = base >> 11;             // GWID = 2048
        const int colbase = base & (GWID - 1);
        #pragma unroll
        for (int j = 0; j < 4; ++j) {
            const int lj = (j == 0) ? lb.x : (j == 1) ? lb.y : (j == 2) ? lb.z : lb.w;
            const int cj = (j == 0) ? g.x  : (j == 1) ? g.y  : (j == 2) ? g.z  : g.w;
            const bool pred = ((unsigned)lj < (unsigned)K_OBJ);
            const unsigned long long act = __ballot(pred);
            if (act == 0ull) continue;
            const int first = __builtin_ctzll(act);
            const int lab0 = __shfl(lj, first);
            const bool uni = __all((!pred) || (lj == lab0));
            if (uni) {
                if (lane == first) {
                    const int last = 63 - __builtin_clzll(act);
                    atomicMin(&s_xmin[lab0], colbase + first * 4 + j);
                    atomicMax(&s_xmax[lab0], colbase + last * 4 + j);
                    atomicMin(&s_ymin[lab0], row);
                    atomicMax(&s_ymax[lab0], row);
                }
                const int key = pred ? cj : -1;
                #pragma unroll
                for (int c = 0; c < NCOLR; ++c) {
                    const unsigned long long m = __ballot(key == c);
                    if (m && lane == first)
                        atomicAdd(&s_hist[lab0 * NCOLR + c], __popcll(m));
                }
            } else {
                if (pred) {
                    atomicAdd(&s_hist[lj * NCOLR + cj], 1);
                    const int xj = colbase + lane * 4 + j;
                    atomicMin(&s_xmin[lj], xj);
                    atomicMax(&s_xmax[lj], xj);
                    atomicMin(&s_ymin[lj], row);
                    atomicMax(&s_ymax[lj], row);
                }
            }
        }
    }
    __syncthreads();
    for (int i = tid; i < K_OBJ * NCOLR; i += RB_TPB) {
        const int v = s_hist[i];
        if (v) atomicAdd(&acc[i], v);
    }
    if (tid < K_OBJ) {
        if (s_ymin[tid] != 0x7fffffff)      atomicMin(&acc[640 + tid], s_ymin[tid]);
        if (s_ymax[tid] != (int)0x80000000) atomicMax(&acc[704 + tid], s_ymax[tid]);
        if (s_xmin[tid] != 0x7fffffff)      atomicMin(&acc[768 + tid], s_xmin[tid]);
        if (s_xmax[tid] != (int)0x80000000) atomicMax(&acc[832 + tid], s_xmax[tid]);
    }
}

__global__ __launch_bounds__(HID) void feats_kernel(
        const int* __restrict__ acc, const float* __restrict__ emb,
        const float* __restrict__ w1, const float* __restrict__ b1,
        const float* __restrict__ w2, const float* __restrict__ b2,
        float* __restrict__ feats) {
    const int k = blockIdx.x;   // object 0..63
    const int d = threadIdx.x;  // dim 0..127
    __shared__ float s_hid[HID];
    __shared__ float s_hist[NCOLR];
    __shared__ float s_geo[4];  // h, w, area_frac, count
    if (d < NCOLR) s_hist[d] = (float)acc[k * NCOLR + d];
    if (d == 0) {
        int cnt = 0;
        for (int c = 0; c < NCOLR; ++c) cnt += acc[k * NCOLR + c];
        s_geo[0] = (float)(acc[704 + k] - acc[640 + k] + 1);
        s_geo[1] = (float)(acc[832 + k] - acc[768 + k] + 1);
        s_geo[2] = (float)cnt / (float)NPIX;
        s_geo[3] = (float)cnt;
    }
    __syncthreads();
    float hv = b1[d] + s_geo[0] * w1[d * 3 + 0] + s_geo[1] * w1[d * 3 + 1]
             + s_geo[2] * w1[d * 3 + 2];
    s_hid[d] = fmaxf(hv, 0.0f);
    __syncthreads();
    float geo = b2[d];
    #pragma unroll 8
    for (int j = 0; j < HID; ++j) geo += s_hid[j] * w2[d * HID + j];
    float ce = 0.0f;
    #pragma unroll
    for (int c = 0; c < NCOLR; ++c) ce += s_hist[c] * emb[c * HID + d];
    const float cnt = s_geo[3];
    ce = (cnt > 0.0f) ? (ce / cnt) : 0.0f;
    feats[k * HID + d] = 0.5f * (ce + geo);
}

#define TPB_ATTN 1024
#define FPAD 136  // feats LDS row stride (words): 16B-aligned, breaks bank conflicts

__global__ __launch_bounds__(TPB_ATTN) void attn_kernel(
        const float* __restrict__ feats, const float* __restrict__ query,
        const float* __restrict__ wqkv, const float* __restrict__ bqkv,
        const float* __restrict__ wo, const float* __restrict__ bo,
        const float* __restrict__ lnw, const float* __restrict__ lnb,
        float* __restrict__ out) {
    __shared__ float s_feats[K_OBJ][FPAD];
    __shared__ float s_q[HID], s_qp[HID], s_u[4][HID], s_cb[4];
    __shared__ float s_attn[4][K_OBJ], s_pool[4][HID], s_oh[HID], s_r[HID];
    __shared__ float s_red[2], s_red2[2];
    const int tid = threadIdx.x;
    for (int i = tid; i < K_OBJ * HID; i += TPB_ATTN)
        s_feats[i >> 7][i & 127] = feats[i];
    if (tid < HID) s_q[tid] = query[tid];
    __syncthreads();
    const float scale = 0.17677669529663687f;  // 1/sqrt(32)

    for (int l = 0; l < 2; ++l) {
        const float* W  = wqkv + l * 384 * HID;
        const float* bq = bqkv + l * 384;
        const int d8 = tid >> 3, p8 = tid & 7;   // 8 threads per 128-dot
        const int i2 = tid >> 1, p2 = tid & 1;   // 2 threads per 32-dot
        const int h2 = i2 >> 7, j2 = i2 & 127;

        // Phase A: qp[d] = s_q . W[d] + bq[d]
        {
            const float4* Wr = (const float4*)(W + d8 * HID + p8 * 16);
            const float4 a0 = Wr[0], a1 = Wr[1], a2 = Wr[2], a3 = Wr[3];
            const float* qv = s_q + p8 * 16;
            float a = a0.x*qv[0] + a0.y*qv[1] + a0.z*qv[2] + a0.w*qv[3]
                    + a1.x*qv[4] + a1.y*qv[5] + a1.z*qv[6] + a1.w*qv[7]
                    + a2.x*qv[8] + a2.y*qv[9] + a2.z*qv[10] + a2.w*qv[11]
                    + a3.x*qv[12] + a3.y*qv[13] + a3.z*qv[14] + a3.w*qv[15];
            a += __shfl_xor(a, 4, 8);
            a += __shfl_xor(a, 2, 8);
            a += __shfl_xor(a, 1, 8);
            if (p8 == 0) s_qp[d8] = a + bq[d8];
        }
        __syncthreads();
        // Phase B: u[h][j] = sum_dd qp[h*32+dd] * Wk[dd_row][j]; cb[h]
        {
            float u = 0.0f;
            const float* qph = s_qp + h2 * 32 + p2 * 16;
            const float* Wc = W + (HID + h2 * 32 + p2 * 16) * HID + j2;
            #pragma unroll
            for (int i = 0; i < 16; ++i) u += qph[i] * Wc[i * HID];
            u += __shfl_xor(u, 1, 2);
            if (p2 == 0) s_u[h2][j2] = u;
        }
        if (tid < 4) {
            float cb = 0.0f;
            #pragma unroll
            for (int dd = 0; dd < 32; ++dd)
                cb += s_qp[tid * 32 + dd] * bq[HID + tid * 32 + dd];
            s_cb[tid] = cb;
        }
        __syncthreads();
        // Phase C: scores[h][k] = scale*(feats[k].u[h] + cb[h])  (4 thr/out)
        {
            const int o = tid >> 2, p = tid & 3;
            const int h = o >> 6, k = o & 63;
            const float* fk = s_feats[k] + p * 32;
            const float* uh = s_u[h] + p * 32;
            float sc = 0.0f;
            #pragma unroll
            for (int i = 0; i < 32; ++i) sc += fk[i] * uh[i];
            sc += __shfl_xor(sc, 2, 4);
            sc += __shfl_xor(sc, 1, 4);
            if (p == 0) s_attn[h][k] = (sc + s_cb[h]) * scale;
        }
        __syncthreads();
        // softmax per head (first 128 threads: 4 heads x 32 lanes)
        if (tid < 128) {
            const int h = tid >> 5, g = tid & 31;
            const float v0 = s_attn[h][g], v1 = s_attn[h][g + 32];
            float m = fmaxf(v0, v1);
            for (int off = 16; off >= 1; off >>= 1)
                m = fmaxf(m, __shfl_xor(m, off, 32));
            const float e0 = expf(v0 - m), e1 = expf(v1 - m);
            float s = e0 + e1;
            for (int off = 16; off >= 1; off >>= 1) s += __shfl_xor(s, off, 32);
            s_attn[h][g] = e0 / s;
            s_attn[h][g + 32] = e1 / s;
        }
        __syncthreads();
        // Phase D: pooled[h][j] = sum_k attn[h][k]*feats[k][j]  (2 thr/out)
        {
            float psum = 0.0f;
            #pragma unroll 8
            for (int k0 = 0; k0 < 32; ++k0) {
                const int k = p2 * 32 + k0;
                psum += s_attn[h2][k] * s_feats[k][j2];
            }
            psum += __shfl_xor(psum, 1, 2);
            if (p2 == 0) s_pool[h2][j2] = psum;
        }
        __syncthreads();
        // Phase E: oh[d] = Wv[d] . pooled[head(d)] + bv[d]  (8 thr/out)
        {
            const int h = d8 >> 5;
            const float4* Wr = (const float4*)(W + (256 + d8) * HID + p8 * 16);
            const float4 a0 = Wr[0], a1 = Wr[1], a2 = Wr[2], a3 = Wr[3];
            const float* pv = s_pool[h] + p8 * 16;
            float a = a0.x*pv[0] + a0.y*pv[1] + a0.z*pv[2] + a0.w*pv[3]
                    + a1.x*pv[4] + a1.y*pv[5] + a1.z*pv[6] + a1.w*pv[7]
                    + a2.x*pv[8] + a2.y*pv[9] + a2.z*pv[10] + a2.w*pv[11]
                    + a3.x*pv[12] + a3.y*pv[13] + a3.z*pv[14] + a3.w*pv[15];
            a += __shfl_xor(a, 4, 8);
            a += __shfl_xor(a, 2, 8);
            a += __shfl_xor(a, 1, 8);
            if (p8 == 0) s_oh[d8] = a + bq[256 + d8];
        }
        __syncthreads();
        // Phase F: r[d] = q[d] + wo[d].oh + bo[d]  (8 thr/out)
        {
            const float4* Wr = (const float4*)(wo + l * HID * HID + d8 * HID + p8 * 16);
            const float4 a0 = Wr[0], a1 = Wr[1], a2 = Wr[2], a3 = Wr[3];
            const float* ov = s_oh + p8 * 16;
            float a = a0.x*ov[0] + a0.y*ov[1] + a0.z*ov[2] + a0.w*ov[3]
                    + a1.x*ov[4] + a1.y*ov[5] + a1.z*ov[6] + a1.w*ov[7]
                    + a2.x*ov[8] + a2.y*ov[9] + a2.z*ov[10] + a2.w*ov[11]
                    + a3.x*ov[12] + a3.y*ov[13] + a3.z*ov[14] + a3.w*ov[15];
            a += __shfl_xor(a, 4, 8);
            a += __shfl_xor(a, 2, 8);
            a += __shfl_xor(a, 1, 8);
            if (p8 == 0) s_r[d8] = s_q[d8] + a + bo[l * HID + d8];
        }
        __syncthreads();
        // LayerNorm (first 128 threads)
        float r_ln = 0.0f, dv = 0.0f;
        if (tid < 128) {
            r_ln = s_r[tid];
            float v = r_ln;
            for (int off = 32; off >= 1; off >>= 1) v += __shfl_xor(v, off, 64);
            if ((tid & 63) == 0) s_red[tid >> 6] = v;
        }
        __syncthreads();
        if (tid < 128) {
            const float mu = (s_red[0] + s_red[1]) * (1.0f / HID);
            dv = r_ln - mu;
            float v2 = dv * dv;
            for (int off = 32; off >= 1; off >>= 1) v2 += __shfl_xor(v2, off, 64);
            if ((tid & 63) == 0) s_red2[tid >> 6] = v2;
        }
        __syncthreads();
        if (tid < 128) {
            const float var = (s_red2[0] + s_red2[1]) * (1.0f / HID);
            s_q[tid] = dv * rsqrtf(var + LN_EPS) * lnw[l * HID + tid]
                     + lnb[l * HID + tid];
        }
        __syncthreads();
    }
    if (tid < HID) out[tid] = s_q[tid];
}

extern "C" void kernel_launch(void* const* d_in, const int* in_sizes, int n_in,
                              void* d_out, int out_size, void* d_ws, size_t ws_size,
                              hipStream_t stream) {
    const int4* grid4 = (const int4*)d_in[0];
    const int4* lab4  = (const int4*)d_in[1];
    const float* emb  = (const float*)d_in[2];
    const float* gw1  = (const float*)d_in[3];
    const float* gb1  = (const float*)d_in[4];
    const float* gw2  = (const float*)d_in[5];
    const float* gb2  = (const float*)d_in[6];
    const float* query = (const float*)d_in[7];
    const float* wqkv = (const float*)d_in[8];
    const float* bqkv = (const float*)d_in[9];
    const float* wo   = (const float*)d_in[10];
    const float* bo   = (const float*)d_in[11];
    const float* lnw  = (const float*)d_in[12];
    const float* lnb  = (const float*)d_in[13];

    int* acc = (int*)d_ws;
    float* feats = (float*)((char*)d_ws + 4096);

    hipLaunchKernelGGL(init_kernel, dim3(1), dim3(1024), 0, stream, acc);
    hipLaunchKernelGGL(reduce_kernel, dim3(RB_BLOCKS), dim3(RB_TPB), 0, stream,
                       grid4, lab4, acc);
    hipLaunchKernelGGL(feats_kernel, dim3(K_OBJ), dim3(HID), 0, stream,
                       acc, emb, gw1, gb1, gw2, gb2, feats);
    hipLaunchKernelGGL(attn_kernel, dim3(1), dim3(TPB_ATTN), 0, stream,
                       feats, query, wqkv, bqkv, wo, bo, lnw, lnb, (float*)d_out);
}